// Round 1
// baseline (889.879 us; speedup 1.0000x reference)
//
#include <hip/hip_runtime.h>
#include <stdint.h>

#define DIM    1024
#define NQ     512     // batch of queries
#define CAP    512     // bucket capacity per query (E[active]=36.8, P(>512)~0)
#define RPB    64      // address rows per block in k1
#define KC     128     // K-chunk (dims) staged to LDS per iteration
#define NCHUNK (DIM / KC)   // 8

// ws layout:
//   [0,      2048)                    int      cnt[512]
//   [2048,   2048+1048576)            uint16   qbf[512][1024]  (bf16 queries)
//   [2048+1048576, +512*512*4)        uint32   buckets[512][CAP]
// total ~2.1 MB (ws is ~1.6 GB per the harness poison fill)

typedef __attribute__((ext_vector_type(8))) short bf16x8;  // 8 bf16 = 4 VGPRs
typedef __attribute__((ext_vector_type(4))) float f32x4;   // MFMA 16x16x32 acc

// k0: convert the 512 query rows f32 -> bf16 (exact for +-1.0: take top 16 bits),
// zero the per-query counters. 512 blocks x 256 threads, one float4 per thread.
__global__ __launch_bounds__(256) void k0_pack(const float* __restrict__ address,
                                               uint32_t* __restrict__ qbf,
                                               int* __restrict__ cnt) {
  const int g = blockIdx.x * 256 + threadIdx.x;          // 0..131071 float4s
  const float4 v = reinterpret_cast<const float4*>(address)[g];
  uint2 u;
  u.x = (__float_as_uint(v.x) >> 16) | (__float_as_uint(v.y) & 0xFFFF0000u);
  u.y = (__float_as_uint(v.z) >> 16) | (__float_as_uint(v.w) & 0xFFFF0000u);
  reinterpret_cast<uint2*>(qbf)[g] = u;
  if (g < NQ) cnt[g] = 0;
}

// k1: bf16 MFMA similarity. Block = 64 address rows x all 512 queries.
// 8 waves; wave w owns queries [64w, 64w+64) x the block's 64 rows:
// 4x4 tiles of mfma_f32_16x16x32_bf16, acc[4][4] of f32x4 (64 VGPRs).
// Addresses are converted f32->bf16 at stage time into XOR-swizzled LDS
// (linear [64][256B] row-major would be a 16-way bank conflict on ds_read_b128;
//  byte ^= (row&7)<<4 spreads it — G4/T2). Queries read from the L2-hot qbf.
// sim is an exact integer in f32, so `sim >= thr` is bit-exact.
__global__ __launch_bounds__(512) void k1_sim(const float* __restrict__ addresses,
                                              const uint32_t* __restrict__ qbf,
                                              const void* __restrict__ thr_raw,
                                              int* __restrict__ cnt,
                                              uint32_t* __restrict__ buckets,
                                              int N) {
  __shared__ uint32_t blds[RPB * KC / 2];   // 64 rows * 128 bf16 = 16 KB
  const int t    = threadIdx.x;
  const int base = blockIdx.x * RPB;

  // Resolve threshold: harness may pass int32 110 or float32 110.0
  int thr;
  {
    const int ti = *reinterpret_cast<const int*>(thr_raw);
    if (ti >= -DIM && ti <= DIM) thr = ti;
    else {
      const float tf = *reinterpret_cast<const float*>(thr_raw);
      thr = (int)floorf(tf + 0.5f);
    }
  }
  const float thrf = (float)thr;

  const int w     = t >> 6;    // wave 0..7 -> query group [64w, 64w+64)
  const int l     = t & 63;
  const int l16   = l & 15;    // MFMA: A row / B col / D col
  const int lk    = l >> 4;    // MFMA k-octet group 0..3
  const int qrow0 = w * 64;

  // staging coords: 8 threads per row, 64 rows
  const int sr   = t >> 3;     // 0..63
  const int sc   = t & 7;      // 0..7
  const int krow = base + sr;

  f32x4 acc[4][4];
#pragma unroll
  for (int mt = 0; mt < 4; ++mt)
#pragma unroll
    for (int nt = 0; nt < 4; ++nt)
      acc[mt][nt] = (f32x4){0.f, 0.f, 0.f, 0.f};

  // T14-style: next chunk's global loads live in regs across the compute phase
  float4 stg[4];
#define LOAD_CHUNK(KCI)                                                              \
  _Pragma("unroll") for (int j = 0; j < 4; ++j) {                                    \
    const int fi = sc + 8 * j;                                                       \
    if (krow < N)                                                                    \
      stg[j] = *reinterpret_cast<const float4*>(                                     \
          addresses + (size_t)krow * DIM + (KCI) * KC + fi * 4);                     \
    else                                                                             \
      stg[j] = make_float4(0.f, 0.f, 0.f, 0.f);                                      \
  }

  LOAD_CHUNK(0);

#pragma unroll 1
  for (int kc = 0; kc < NCHUNK; ++kc) {
    // write staged chunk to LDS (f32 -> bf16 = top 16 bits; exact for +-1.0)
#pragma unroll
    for (int j = 0; j < 4; ++j) {
      const int fi = sc + 8 * j;
      uint2 u;
      u.x = (__float_as_uint(stg[j].x) >> 16) | (__float_as_uint(stg[j].y) & 0xFFFF0000u);
      u.y = (__float_as_uint(stg[j].z) >> 16) | (__float_as_uint(stg[j].w) & 0xFFFF0000u);
      const int lbyte = (sr * 256 + fi * 8) ^ ((sr & 7) << 4);
      *reinterpret_cast<uint2*>(reinterpret_cast<char*>(blds) + lbyte) = u;
    }
    __syncthreads();

    if (kc + 1 < NCHUNK) LOAD_CHUNK(kc + 1);  // issue; lands under the MFMAs

#pragma unroll
    for (int ks = 0; ks < 4; ++ks) {          // 4 k-steps of 32 dims
      bf16x8 a[4], b[4];
      const int kglob = kc * KC + ks * 32 + lk * 8;
#pragma unroll
      for (int mt = 0; mt < 4; ++mt) {        // A: lane l16 = query row in tile
        const int q = qrow0 + mt * 16 + l16;
        a[mt] = *reinterpret_cast<const bf16x8*>(
            reinterpret_cast<const char*>(qbf) + ((size_t)q * DIM + kglob) * 2);
      }
#pragma unroll
      for (int nt = 0; nt < 4; ++nt) {        // B: lane l16 = address row in tile
        const int n = nt * 16 + l16;
        const int lbyte = (n * 256 + (ks * 32 + lk * 8) * 2) ^ ((n & 7) << 4);
        b[nt] = *reinterpret_cast<const bf16x8*>(
            reinterpret_cast<const char*>(blds) + lbyte);
      }
#pragma unroll
      for (int mt = 0; mt < 4; ++mt)
#pragma unroll
        for (int nt = 0; nt < 4; ++nt)
          acc[mt][nt] = __builtin_amdgcn_mfma_f32_16x16x32_bf16(
              a[mt], b[nt], acc[mt][nt], 0, 0, 0);
    }
    __syncthreads();
  }
#undef LOAD_CHUNK

  // epilogue: D layout (verified m89/m91): col = lane&15, row = (lane>>4)*4 + r
#pragma unroll
  for (int mt = 0; mt < 4; ++mt) {
#pragma unroll
    for (int nt = 0; nt < 4; ++nt) {
      const int n = base + nt * 16 + l16;
#pragma unroll
      for (int r = 0; r < 4; ++r) {
        const float s = acc[mt][nt][r];
        if (s >= thrf && n < N) {
          const int q   = qrow0 + mt * 16 + lk * 4 + r;
          const int idx = atomicAdd(&cnt[q], 1);   // device-scope, cross-XCD safe
          if (idx < CAP) buckets[(size_t)q * CAP + idx] = (uint32_t)n;
        }
      }
    }
  }
}

// k2: one block per query. Sum the ~37 active content rows (f64 accumulate to
// keep the sign exact), write sign. Every output element is written.
__global__ __launch_bounds__(256) void k2_gather(const float* __restrict__ content,
                                                 const int* __restrict__ cnt,
                                                 const uint32_t* __restrict__ buckets,
                                                 float* __restrict__ out) {
  __shared__ uint32_t list[CAP];
  const int b = blockIdx.x;
  const int t = threadIdx.x;
  int c = cnt[b];
  if (c > CAP) c = CAP;
  for (int i = t; i < c; i += 256) list[i] = buckets[(size_t)b * CAP + i];
  __syncthreads();

  double a0 = 0, a1 = 0, a2 = 0, a3 = 0;
  const float4* __restrict__ c4 = reinterpret_cast<const float4*>(content);
  for (int i = 0; i < c; ++i) {
    const float4 v = c4[(size_t)list[i] * (DIM / 4) + t];  // coalesced
    a0 += v.x; a1 += v.y; a2 += v.z; a3 += v.w;
  }
  float4 r;
  r.x = a0 > 0.0 ? 1.0f : (a0 < 0.0 ? -1.0f : 0.0f);
  r.y = a1 > 0.0 ? 1.0f : (a1 < 0.0 ? -1.0f : 0.0f);
  r.z = a2 > 0.0 ? 1.0f : (a2 < 0.0 ? -1.0f : 0.0f);
  r.w = a3 > 0.0 ? 1.0f : (a3 < 0.0 ? -1.0f : 0.0f);
  reinterpret_cast<float4*>(out)[(size_t)b * (DIM / 4) + t] = r;
}

extern "C" void kernel_launch(void* const* d_in, const int* in_sizes, int n_in,
                              void* d_out, int out_size, void* d_ws, size_t ws_size,
                              hipStream_t stream) {
  const float* address   = (const float*)d_in[0];
  const float* addresses = (const float*)d_in[1];
  const float* content   = (const float*)d_in[2];
  const void*  thr       = d_in[3];
  const int N = in_sizes[1] / DIM;  // 100000

  char* ws = (char*)d_ws;
  int*      cnt     = (int*)ws;                                   // 2 KB
  uint32_t* qbf     = (uint32_t*)(ws + 2048);                     // 1 MB bf16 queries
  uint32_t* buckets = (uint32_t*)(ws + 2048 + NQ * DIM * 2);      // 1 MB

  k0_pack<<<512, 256, 0, stream>>>(address, qbf, cnt);
  const int nb = (N + RPB - 1) / RPB;
  k1_sim<<<nb, 512, 0, stream>>>(addresses, qbf, thr, cnt, buckets, N);
  k2_gather<<<NQ, 256, 0, stream>>>(content, cnt, buckets, (float*)d_out);
}

// Round 2
// 794.946 us; speedup vs baseline: 1.1194x; 1.1194x over previous
//
#include <hip/hip_runtime.h>
#include <stdint.h>

#define DIM    1024
#define NQ     512       // batch of queries
#define CAP    512       // bucket capacity per query (E[active]=36.8)
#define QT     128       // queries per k1 block  (4 qtiles)
#define NT     128       // address rows per k1 block
#define BK     128       // dims per K-step (fp8: 128 bytes)
#define KSTEPS (DIM/BK)  // 8
#define NTILES 782       // ceil(100000/128)
#define NPAD   (NTILES*NT)  // 100096

// ws layout:
//   [0,      2048)                 int     cnt[512]
//   [2048,   2048+524288)          uint8   qf8[512][1024]      (fp8 queries, swizzled)
//   [526336, 526336+1048576)       uint32  buckets[512][CAP]
//   [1574912, +NPAD*1024)          uint8   abf8[100096][1024]  (fp8 addresses, swizzled)
// total ~104 MB  (ws is ~1.6 GB)
//
// Swizzled global layout (both qf8 and abf8): the 16B block holding dims
// [d0, d0+16) of row n lives at byte n*1024 + (d0 ^ ((n&7)<<4)).  XOR touches
// bits 4-6 only, so blocks permute within each 128B K-chunk.  A linear
// global_load_lds copy of a [128 rows x 128B] K-chunk then lands XOR-swizzled
// in LDS, and the ds_read_b64 fragment pattern (16 lanes, same col, rows
// 0..15) spreads across all 32 banks (2-way = free).

typedef __attribute__((ext_vector_type(4))) float f32x4;

// fp8 e4m3fn: +1.0 = 0x38, -1.0 = 0xB8  -> byte = 0x38 | (signbit<<7)
__device__ __forceinline__ uint32_t pack4(const float4 v) {
  return ( ((__float_as_uint(v.x) >> 31 << 7) | 0x38u)       )
       | ( ((__float_as_uint(v.y) >> 31 << 7) | 0x38u) <<  8 )
       | ( ((__float_as_uint(v.z) >> 31 << 7) | 0x38u) << 16 )
       | ( ((__float_as_uint(v.w) >> 31 << 7) | 0x38u) << 24 );
}

// k0: queries f32 -> fp8 swizzled; zero counters. 32768 threads (512 rows x 64 blocks).
__global__ __launch_bounds__(256) void k0_queries(const float* __restrict__ address,
                                                  uint8_t* __restrict__ qf8,
                                                  int* __restrict__ cnt) {
  const int g = blockIdx.x * 256 + threadIdx.x;
  const int n = g >> 6, d0 = (g & 63) * 16;
  const float4* src = reinterpret_cast<const float4*>(address + (size_t)n * DIM + d0);
  uint4 o;
  o.x = pack4(src[0]); o.y = pack4(src[1]); o.z = pack4(src[2]); o.w = pack4(src[3]);
  *reinterpret_cast<uint4*>(qf8 + (size_t)n * DIM + (d0 ^ ((n & 7) << 4))) = o;
  if (g < NQ) cnt[g] = 0;
}

// k1a: addresses f32 -> fp8 swizzled; pad rows [N, NPAD) zeroed (fp8 0 = +0.0,
// sim contribution 0 -> never active). Reads fully coalesced (64B/lane bursts);
// writes coalesced (XOR permutes 16B blocks within each 128B chunk).
__global__ __launch_bounds__(256) void k1a_convert(const float* __restrict__ addresses,
                                                   uint8_t* __restrict__ abf8,
                                                   int N) {
  const int g = blockIdx.x * 256 + threadIdx.x;   // exactly NPAD*64 threads
  const int n = g >> 6, d0 = (g & 63) * 16;
  uint4 o = make_uint4(0u, 0u, 0u, 0u);
  if (n < N) {
    const float4* src = reinterpret_cast<const float4*>(addresses + (size_t)n * DIM + d0);
    o.x = pack4(src[0]); o.y = pack4(src[1]); o.z = pack4(src[2]); o.w = pack4(src[3]);
  }
  *reinterpret_cast<uint4*>(abf8 + (size_t)n * DIM + (d0 ^ ((n & 7) << 4))) = o;
}

// k1: fp8 MFMA presence test, m97-style. Block = 128q x 128n, 4 waves, each
// wave owns a 64x64 quadrant (4x4 frags of 16x16x32_fp8_fp8). Double-buffered
// global_load_lds staging of both operands, one barrier per K-step.
__global__ __launch_bounds__(256, 2) void k1_sim(const uint8_t* __restrict__ abf8,
                                                 const uint8_t* __restrict__ qf8,
                                                 const void* __restrict__ thr_raw,
                                                 int* __restrict__ cnt,
                                                 uint32_t* __restrict__ buckets,
                                                 int N) {
  __shared__ __align__(16) uint8_t lds[2][2][QT * BK];  // [buf][A/B][16384] = 64 KB
  const int t  = threadIdx.x;
  const int qt = blockIdx.x;        // 0..3
  const int nt = blockIdx.y;        // 0..781
  const int w  = t >> 6, l = t & 63;

  // threshold: harness may pass int32 110 or float32 110.0
  int thr;
  {
    const int ti = *reinterpret_cast<const int*>(thr_raw);
    if (ti >= -DIM && ti <= DIM) thr = ti;
    else thr = (int)floorf(*reinterpret_cast<const float*>(thr_raw) + 0.5f);
  }
  const float thrf = (float)thr;

  const uint8_t* __restrict__ Abase = qf8  + (size_t)(qt * QT) * DIM;
  const uint8_t* __restrict__ Bbase = abf8 + (size_t)(nt * NT) * DIM;

  // stage K-step s into buf: linear 16KB copy per operand; global layout is
  // pre-swizzled so LDS image is the swizzled tile. 8 gload_lds / thread.
  auto stage = [&](int buf, int s) {
#pragma unroll
    for (int i = 0; i < 4; ++i) {
      const int D = w * 4096 + i * 1024 + l * 16;  // lds byte; lane-linear per inst
      const int r = D >> 7;                        // tile row 0..127
      const int c = D & 127;                       // byte col (16B aligned)
      __builtin_amdgcn_global_load_lds(
          (const __attribute__((address_space(1))) void*)(Abase + (size_t)r * DIM + s * BK + c),
          (__attribute__((address_space(3))) void*)(&lds[buf][0][D]), 16, 0, 0);
      __builtin_amdgcn_global_load_lds(
          (const __attribute__((address_space(1))) void*)(Bbase + (size_t)r * DIM + s * BK + c),
          (__attribute__((address_space(3))) void*)(&lds[buf][1][D]), 16, 0, 0);
    }
  };

  f32x4 acc[4][4];
#pragma unroll
  for (int mt = 0; mt < 4; ++mt)
#pragma unroll
    for (int ntt = 0; ntt < 4; ++ntt)
      acc[mt][ntt] = (f32x4){0.f, 0.f, 0.f, 0.f};

  const int wr   = (w >> 1) * 64;   // query offset within tile
  const int wc   = (w & 1) * 64;    // address-row offset within tile
  const int l15  = l & 15;
  const int swz  = (l & 7) << 4;    // == ((row&7)<<4) since row = base16 + l15
  const int goct = (l >> 4) * 8;    // k-octet byte offset

  stage(0, 0);
  int cur = 0;
#pragma unroll 1
  for (int s = 0; s < KSTEPS; ++s) {
    __syncthreads();                 // (compiler drains vmcnt) buf[cur] ready
    if (s + 1 < KSTEPS) stage(cur ^ 1, s + 1);   // prefetch lands under MFMAs
    const uint8_t* __restrict__ A = lds[cur][0];
    const uint8_t* __restrict__ B = lds[cur][1];
#pragma unroll
    for (int ks = 0; ks < 4; ++ks) {
      const int cbase = (ks * 32 + goct) ^ swz;
      long a[4], b[4];
#pragma unroll
      for (int mt = 0; mt < 4; ++mt)
        a[mt] = *reinterpret_cast<const long*>(A + (wr + mt * 16 + l15) * BK + cbase);
#pragma unroll
      for (int ntt = 0; ntt < 4; ++ntt)
        b[ntt] = *reinterpret_cast<const long*>(B + (wc + ntt * 16 + l15) * BK + cbase);
#pragma unroll
      for (int mt = 0; mt < 4; ++mt)
#pragma unroll
        for (int ntt = 0; ntt < 4; ++ntt)
          acc[mt][ntt] = __builtin_amdgcn_mfma_f32_16x16x32_fp8_fp8(
              a[mt], b[ntt], acc[mt][ntt], 0, 0, 0);
    }
    cur ^= 1;
  }

  // epilogue: D col = lane&15 (n), row = (lane>>4)*4 + r (q) — dtype-independent
  const int nb = nt * NT + wc;
  const int qb = qt * QT + wr + (l >> 4) * 4;
#pragma unroll
  for (int mt = 0; mt < 4; ++mt) {
#pragma unroll
    for (int ntt = 0; ntt < 4; ++ntt) {
      const int n = nb + ntt * 16 + l15;
#pragma unroll
      for (int r = 0; r < 4; ++r) {
        if (acc[mt][ntt][r] >= thrf && n < N) {
          const int q   = qb + mt * 16 + r;
          const int idx = atomicAdd(&cnt[q], 1);   // device-scope, cross-XCD safe
          if (idx < CAP) buckets[(size_t)q * CAP + idx] = (uint32_t)n;
        }
      }
    }
  }
}

// k2: one block per query. Sum the ~37 active content rows (f64 accumulate to
// keep the sign exact), write sign. Every output element is written.
__global__ __launch_bounds__(256) void k2_gather(const float* __restrict__ content,
                                                 const int* __restrict__ cnt,
                                                 const uint32_t* __restrict__ buckets,
                                                 float* __restrict__ out) {
  __shared__ uint32_t list[CAP];
  const int b = blockIdx.x;
  const int t = threadIdx.x;
  int c = cnt[b];
  if (c > CAP) c = CAP;
  for (int i = t; i < c; i += 256) list[i] = buckets[(size_t)b * CAP + i];
  __syncthreads();

  double a0 = 0, a1 = 0, a2 = 0, a3 = 0;
  const float4* __restrict__ c4 = reinterpret_cast<const float4*>(content);
  for (int i = 0; i < c; ++i) {
    const float4 v = c4[(size_t)list[i] * (DIM / 4) + t];  // coalesced
    a0 += v.x; a1 += v.y; a2 += v.z; a3 += v.w;
  }
  float4 r;
  r.x = a0 > 0.0 ? 1.0f : (a0 < 0.0 ? -1.0f : 0.0f);
  r.y = a1 > 0.0 ? 1.0f : (a1 < 0.0 ? -1.0f : 0.0f);
  r.z = a2 > 0.0 ? 1.0f : (a2 < 0.0 ? -1.0f : 0.0f);
  r.w = a3 > 0.0 ? 1.0f : (a3 < 0.0 ? -1.0f : 0.0f);
  reinterpret_cast<float4*>(out)[(size_t)b * (DIM / 4) + t] = r;
}

extern "C" void kernel_launch(void* const* d_in, const int* in_sizes, int n_in,
                              void* d_out, int out_size, void* d_ws, size_t ws_size,
                              hipStream_t stream) {
  const float* address   = (const float*)d_in[0];
  const float* addresses = (const float*)d_in[1];
  const float* content   = (const float*)d_in[2];
  const void*  thr       = d_in[3];
  const int N = in_sizes[1] / DIM;  // 100000

  char* ws = (char*)d_ws;
  int*      cnt     = (int*)ws;                           // 2 KB
  uint8_t*  qf8     = (uint8_t*)(ws + 2048);              // 512 KB
  uint32_t* buckets = (uint32_t*)(ws + 526336);           // 1 MB
  uint8_t*  abf8    = (uint8_t*)(ws + 1574912);           // 102.5 MB

  k0_queries<<<128, 256, 0, stream>>>(address, qf8, cnt);
  k1a_convert<<<(NPAD * 64) / 256, 256, 0, stream>>>(addresses, abf8, N);
  k1_sim<<<dim3(4, NTILES), 256, 0, stream>>>(abf8, qf8, thr, cnt, buckets, N);
  k2_gather<<<NQ, 256, 0, stream>>>(content, cnt, buckets, (float*)d_out);
}